// Round 1
// baseline (465.689 us; speedup 1.0000x reference)
//
#include <hip/hip_runtime.h>

// Problem constants
#define BB 32
#define CC 128
#define HW 1024            // 32*32
#define NN 32768           // BB*HW
#define KK 1024            // num embeddings
#define DD 128             // embedding dim
// Output offsets (floats): (loss, quantized_nchw, perplexity, encodings, top_k_quantized)
#define OFF_QUANT 1
#define OFF_PERP  4194305
#define OFF_ENC   4194306
#define OFF_TOPK  37748738

// ws layout (bytes)
#define WS_PARTIALS 0          // 4096 doubles = 32768 B
#define WS_HIST     32768      // 1024 ints   = 4096 B
#define WS_CAND8    36864      // 32768*8 ints = 1 MiB
#define WS_TOP3     1085440    // 32768*4 ints = 512 KiB

__device__ __forceinline__ bool lessdi(float d, int e, float dr, int er) {
    return (d < dr) || (d == dr && e < er);
}

// ---------------------------------------------------------------------------
// Kernel A: fp32 candidate pass. 64 rows x 1024 embs per block, tiles of 64
// embs staged in LDS. Ranks by s = ||e||^2 - 2*x.e (row-constant ||x||^2
// dropped). Per-thread top-3 over its 64 embs -> merged top-8 -> ws.
// LDS: x 32KB [k][row] + e 32KB [k][col] (XOR-swizzled) = 64KB, 2 blk/CU.
// ---------------------------------------------------------------------------
__global__ __launch_bounds__(256) void kA_candidates(
    const float* __restrict__ in, const float* __restrict__ emb,
    int* __restrict__ cand8)
{
    __shared__ float lds[16384];           // 64 KB
    float* x_lds = lds;                    // [128][64]
    float* e_lds = lds + 8192;             // [128][64] swizzled

    const int t    = threadIdx.x;
    const int lane = t & 63;
    const int wv   = t >> 6;
    const int rowBase = blockIdx.x * 64;
    const int b   = rowBase >> 10;
    const int hw0 = rowBase & 1023;
    const float* inB = in + (size_t)b * (CC * HW) + hw0;

    // stage x tile: coalesced (64 consecutive hw per c)
    for (int i = t; i < 8192; i += 256) {
        int c = i >> 6, r = i & 63;
        x_lds[c * 64 + r] = inB[c * HW + r];
    }

    const int tr  = lane & 15;             // row group (4 rows)
    const int teL = lane >> 4;             // 0..3
    const int te  = wv * 4 + teL;          // emb group (4 embs), 0..15
    const int m   = lane & 15;             // staging: emb-in-16
    const int qc  = lane >> 4;             // staging: c-chunk of 32

    const float4* x4 = (const float4*)x_lds;
    const float4* e4 = (const float4*)e_lds;

    float d0[4], d1[4], d2[4];
    int   i0[4], i1[4], i2[4];
#pragma unroll
    for (int i = 0; i < 4; ++i) {
        d0[i] = d1[i] = d2[i] = 3.4e38f;
        i0[i] = i1[i] = i2[i] = 0x7fffffff;
    }

    for (int tile = 0; tile < 16; ++tile) {
        __syncthreads();   // x ready / previous tile's compute done
        // stage e tile (64 embs) + per-emb norm; perfectly coalesced global
        const int eloc = 16 * wv + m;                    // 0..63
        const int col  = eloc ^ ((qc & 1) << 4);         // element-level XOR-16 swizzle
        const float4* er = (const float4*)(emb + (size_t)(tile * 64 + eloc) * DD + qc * 32);
        float en = 0.f;
#pragma unroll
        for (int u = 0; u < 8; ++u) {
            float4 v = er[u];
            en = fmaf(v.x, v.x, en); en = fmaf(v.y, v.y, en);
            en = fmaf(v.z, v.z, en); en = fmaf(v.w, v.w, en);
            int c0 = qc * 32 + u * 4;
            e_lds[(c0 + 0) * 64 + col] = v.x;
            e_lds[(c0 + 1) * 64 + col] = v.y;
            e_lds[(c0 + 2) * 64 + col] = v.z;
            e_lds[(c0 + 3) * 64 + col] = v.w;
        }
        en += __shfl_xor(en, 16);
        en += __shfl_xor(en, 32);   // all 4 chunk-copies now hold enorm[16*wv+m]
        __syncthreads();

        // 4x4 register micro-tile over k
        float acc[4][4];
#pragma unroll
        for (int i = 0; i < 4; ++i)
#pragma unroll
            for (int j = 0; j < 4; ++j) acc[i][j] = 0.f;

#pragma unroll 4
        for (int k = 0; k < 128; ++k) {
            float4 xv = x4[k * 16 + tr];
            float4 ev = e4[k * 16 + (te ^ (((k >> 5) & 1) << 2))];
            float xs[4] = {xv.x, xv.y, xv.z, xv.w};
            float es[4] = {ev.x, ev.y, ev.z, ev.w};
#pragma unroll
            for (int i = 0; i < 4; ++i)
#pragma unroll
                for (int j = 0; j < 4; ++j)
                    acc[i][j] = fmaf(xs[i], es[j], acc[i][j]);
        }

        // tile epilogue: s = enorm - 2*dot, insert into per-row top-3
#pragma unroll
        for (int j = 0; j < 4; ++j) {
            float enj = __shfl(en, 4 * teL + j);   // lane (4*teL+j) holds that emb's norm
            int eg = tile * 64 + 4 * te + j;
#pragma unroll
            for (int i = 0; i < 4; ++i) {
                float s = fmaf(-2.f, acc[i][j], enj);
                bool c0 = lessdi(s, eg, d0[i], i0[i]);
                bool c1 = lessdi(s, eg, d1[i], i1[i]);
                bool c2 = lessdi(s, eg, d2[i], i2[i]);
                d2[i] = c1 ? d1[i] : (c2 ? s : d2[i]); i2[i] = c1 ? i1[i] : (c2 ? eg : i2[i]);
                d1[i] = c0 ? d0[i] : (c1 ? s : d1[i]); i1[i] = c0 ? i0[i] : (c1 ? eg : i1[i]);
                d0[i] = c0 ? s : d0[i];                i0[i] = c0 ? eg : i0[i];
            }
        }
    }
    __syncthreads();

    // dump per-thread top-3 into LDS (aliases x region; x dead now)
    float* cd = lds;                        // [64][16][3] dists
    int*   ci = (int*)(lds + 3072);         // [64][16][3] idx
#pragma unroll
    for (int i = 0; i < 4; ++i) {
        int row  = 4 * tr + i;
        int base = (row * 16 + te) * 3;
        cd[base + 0] = d0[i]; ci[base + 0] = i0[i];
        cd[base + 1] = d1[i]; ci[base + 1] = i1[i];
        cd[base + 2] = d2[i]; ci[base + 2] = i2[i];
    }
    __syncthreads();

    // merge 48 candidates -> top-8 guard band, one thread per row
    if (t < 64) {
        float D[8]; int I[8];
#pragma unroll
        for (int s = 0; s < 8; ++s) { D[s] = 3.4e38f; I[s] = 0x7fffffff; }
        for (int s = 0; s < 48; ++s) {
            float dv = cd[t * 48 + s];
            int   ev = ci[t * 48 + s];
            if (lessdi(dv, ev, D[7], I[7])) {
                D[7] = dv; I[7] = ev;
#pragma unroll
                for (int u = 7; u > 0; --u) {
                    if (lessdi(D[u], I[u], D[u - 1], I[u - 1])) {
                        float td = D[u]; D[u] = D[u - 1]; D[u - 1] = td;
                        int   ti = I[u]; I[u] = I[u - 1]; I[u - 1] = ti;
                    }
                }
            }
        }
        int n = rowBase + t;
#pragma unroll
        for (int s = 0; s < 8; ++s) cand8[n * 8 + s] = I[s];
    }
}

// ---------------------------------------------------------------------------
// Kernel B: fp64 exact refine of 8 candidates -> true top-3 (tie-break by
// lower index, matching jax.lax.top_k stability). Also builds the histogram
// of the 3rd-nearest index for perplexity.
// ---------------------------------------------------------------------------
__global__ __launch_bounds__(256) void kB_refine(
    const float* __restrict__ in, const float* __restrict__ emb,
    const int* __restrict__ cand8, int* __restrict__ top3, int* __restrict__ hist)
{
    __shared__ float x_lds[8192];   // [128][64]
    const int t = threadIdx.x;
    const int rowBase = blockIdx.x * 64;
    const int b = rowBase >> 10, hw0 = rowBase & 1023;
    const float* inB = in + (size_t)b * (CC * HW) + hw0;
    for (int i = t; i < 8192; i += 256) {
        int c = i >> 6, r = i & 63;
        x_lds[c * 64 + r] = inB[c * HW + r];
    }
    __syncthreads();

    const int r = t >> 2;     // row 0..63
    const int q = t & 3;      // c-chunk of 32
    const int n = rowBase + r;

    double dist[8]; int es[8];
    for (int s = 0; s < 8; ++s) {
        int e = cand8[n * 8 + s];
        es[s] = e;
        const float4* er = (const float4*)(emb + (size_t)e * DD + q * 32);
        double acc = 0.0;
#pragma unroll
        for (int u = 0; u < 8; ++u) {
            float4 ev = er[u];
            int c0 = q * 32 + u * 4;
            double a0 = (double)x_lds[(c0 + 0) * 64 + r] - (double)ev.x;
            double a1 = (double)x_lds[(c0 + 1) * 64 + r] - (double)ev.y;
            double a2 = (double)x_lds[(c0 + 2) * 64 + r] - (double)ev.z;
            double a3 = (double)x_lds[(c0 + 3) * 64 + r] - (double)ev.w;
            acc += a0 * a0 + a1 * a1 + a2 * a2 + a3 * a3;
        }
        acc += __shfl_xor(acc, 1);
        acc += __shfl_xor(acc, 2);
        dist[s] = acc;
    }

    if (q == 0) {
        bool used[8] = {false, false, false, false, false, false, false, false};
        int out_idx[3];
#pragma unroll
        for (int p = 0; p < 3; ++p) {
            double bd = 1.0e300; int bi = 0x7fffffff, bs = 0;
            for (int s = 0; s < 8; ++s) {
                if (used[s]) continue;
                if (dist[s] < bd || (dist[s] == bd && es[s] < bi)) {
                    bd = dist[s]; bi = es[s]; bs = s;
                }
            }
            used[bs] = true; out_idx[p] = bi;
        }
        top3[n * 4 + 0] = out_idx[0];
        top3[n * 4 + 1] = out_idx[1];
        top3[n * 4 + 2] = out_idx[2];
        atomicAdd(&hist[out_idx[2]], 1);
    }
}

// ---------------------------------------------------------------------------
// Kernel C: quantized_nchw write (gather emb[idx0][c]) + fp64 loss partials.
// Element j maps 1:1 to input layout [b][c][hw] -> coalesced in/out.
// ---------------------------------------------------------------------------
__global__ __launch_bounds__(256) void kC_quant_loss(
    const float* __restrict__ in, const float* __restrict__ emb,
    const int* __restrict__ top3, float* __restrict__ out,
    double* __restrict__ partials)
{
    const int t = threadIdx.x, bid = blockIdx.x;
    double acc = 0.0;
#pragma unroll
    for (int u = 0; u < 4; ++u) {
        int j  = bid * 1024 + u * 256 + t;
        int hw = j & 1023;
        int c  = (j >> 10) & 127;
        int bb = j >> 17;
        int n  = bb * 1024 + hw;
        int e  = top3[n * 4];
        float qv = emb[e * DD + c];
        float xv = in[j];
        out[OFF_QUANT + j] = qv;
        double d = (double)qv - (double)xv;
        acc += d * d;
    }
#pragma unroll
    for (int o = 1; o < 64; o <<= 1) acc += __shfl_xor(acc, o);
    __shared__ double wsum[4];
    if ((t & 63) == 0) wsum[t >> 6] = acc;
    __syncthreads();
    if (t == 0) partials[bid] = wsum[0] + wsum[1] + wsum[2] + wsum[3];
}

// ---------------------------------------------------------------------------
// Kernel D: top_k_quantized [3][N][128] — coalesced float2 gather/store.
// ---------------------------------------------------------------------------
__global__ __launch_bounds__(256) void kD_topk(
    const float* __restrict__ emb, const int* __restrict__ top3,
    float* __restrict__ out)
{
    int j  = blockIdx.x * 256 + threadIdx.x;   // float2 units, 3*32768*64 total
    int c2 = j & 63;
    int n  = (j >> 6) & 32767;
    int k  = j >> 21;
    int e  = top3[n * 4 + k];
    const float2* e2 = (const float2*)emb;
    ((float2*)(out + OFF_TOPK))[j] = e2[e * 64 + c2];
}

// ---------------------------------------------------------------------------
// Kernel E: encodings scatter (region pre-zeroed by memset).
// ---------------------------------------------------------------------------
__global__ __launch_bounds__(256) void kE_scatter(
    const int* __restrict__ top3, float* __restrict__ out)
{
    int n = blockIdx.x * 256 + threadIdx.x;
    int e = top3[n * 4 + 2];
    out[(size_t)OFF_ENC + (size_t)n * KK + e] = 1.0f;
}

// ---------------------------------------------------------------------------
// Kernel F: finalize loss + perplexity (fp64 reductions).
// ---------------------------------------------------------------------------
__global__ __launch_bounds__(1024) void kF_final(
    const double* __restrict__ partials, const int* __restrict__ hist,
    float* __restrict__ out)
{
    __shared__ double sred[1024];
    const int t = threadIdx.x;
    double a = partials[t] + partials[t + 1024] + partials[t + 2048] + partials[t + 3072];
    sred[t] = a;
    __syncthreads();
    for (int s = 512; s > 0; s >>= 1) {
        if (t < s) sred[t] += sred[t + s];
        __syncthreads();
    }
    if (t == 0) out[0] = (float)(0.25 * sred[0] / 4194304.0);
    __syncthreads();
    double p = (double)hist[t] / 32768.0;
    sred[t] = p * log(p + 1e-10);
    __syncthreads();
    for (int s = 512; s > 0; s >>= 1) {
        if (t < s) sred[t] += sred[t + s];
        __syncthreads();
    }
    if (t == 0) out[OFF_PERP] = (float)exp(-sred[0]);
}

extern "C" void kernel_launch(void* const* d_in, const int* in_sizes, int n_in,
                              void* d_out, int out_size, void* d_ws, size_t ws_size,
                              hipStream_t stream)
{
    const float* in  = (const float*)d_in[0];
    const float* emb = (const float*)d_in[1];
    float* out = (float*)d_out;
    char*  ws  = (char*)d_ws;

    double* partials = (double*)(ws + WS_PARTIALS);   // 4096 doubles
    int*    hist     = (int*)(ws + WS_HIST);          // 1024 ints
    int*    cand8    = (int*)(ws + WS_CAND8);         // 32768*8 ints
    int*    top3     = (int*)(ws + WS_TOP3);          // 32768*4 ints

    // zero encodings region and histogram
    hipMemsetAsync(out + OFF_ENC, 0, (size_t)NN * KK * sizeof(float), stream);
    hipMemsetAsync(hist, 0, KK * sizeof(int), stream);

    kA_candidates<<<dim3(512), dim3(256), 0, stream>>>(in, emb, cand8);
    kB_refine    <<<dim3(512), dim3(256), 0, stream>>>(in, emb, cand8, top3, hist);
    kC_quant_loss<<<dim3(4096), dim3(256), 0, stream>>>(in, emb, top3, out, partials);
    kD_topk      <<<dim3(24576), dim3(256), 0, stream>>>(emb, top3, out);
    kE_scatter   <<<dim3(128), dim3(256), 0, stream>>>(top3, out);
    kF_final     <<<dim3(1), dim3(1024), 0, stream>>>(partials, hist, out);
}

// Round 2
// 357.478 us; speedup vs baseline: 1.3027x; 1.3027x over previous
//
#include <hip/hip_runtime.h>

// Problem constants
#define BB 32
#define CC 128
#define HW 1024            // 32*32
#define NN 32768           // BB*HW
#define KK 1024            // num embeddings
#define DD 128             // embedding dim
// Output offsets (floats): (loss, quantized_nchw, perplexity, encodings, top_k_quantized)
#define OFF_QUANT 1
#define OFF_PERP  4194305
#define OFF_ENC   4194306
#define OFF_TOPK  37748738

// ws layout (bytes)
#define WS_PARTIALS 0          // 4096 doubles = 32768 B
#define WS_HIST     32768      // 1024 ints   = 4096 B
#define WS_CAND8    36864      // 32768*8 ints = 1 MiB
#define WS_TOP3     1085440    // 32768*4 ints = 512 KiB
#define WS_EMBBF    1609728    // 1024*128 ushort = 256 KiB
#define WS_ENORM    1871872    // 1024 float = 4 KiB

typedef __attribute__((ext_vector_type(8))) short short8;
typedef __attribute__((ext_vector_type(4))) float f32x4;

__device__ __forceinline__ ushort f32_to_bf16(float v) {
    uint u = __float_as_uint(v);
    u = (u + 0x7FFFu + ((u >> 16) & 1u)) >> 16;   // RNE
    return (ushort)u;
}

__device__ __forceinline__ bool lessdi(float d, int e, float dr, int er) {
    return (d < dr) || (d == dr && e < er);
}

// ---------------------------------------------------------------------------
// kX: x fp32 NCHW -> xbf bf16 [N][128]  (N = b*1024 + hw, d = c)
// Thread t owns output row n; reads are coalesced across lanes per-c.
// xbf lives in the (not yet written) top_k output region.
// ---------------------------------------------------------------------------
__global__ __launch_bounds__(256) void kX_convert(
    const float* __restrict__ in, ushort* __restrict__ xbf)
{
    const int n  = blockIdx.x * 256 + threadIdx.x;
    const int b  = n >> 10, hw = n & 1023;
    const float* src = in + (size_t)b * (CC * HW) + hw;
    short8* dst = (short8*)(xbf + (size_t)n * 128);
#pragma unroll 2
    for (int c0 = 0; c0 < 16; ++c0) {
        union { short8 v; ushort u[8]; } p;
#pragma unroll
        for (int j = 0; j < 8; ++j)
            p.u[j] = f32_to_bf16(src[(size_t)(c0 * 8 + j) * HW]);
        dst[c0] = p.v;
    }
}

// ---------------------------------------------------------------------------
// kXe: emb fp32 -> embbf bf16 [1024][128] + fp32 row norms.
// 4 threads per row, fully coalesced float4 loads / 16B stores.
// ---------------------------------------------------------------------------
__global__ __launch_bounds__(256) void kXe_convert(
    const float* __restrict__ emb, ushort* __restrict__ embbf,
    float* __restrict__ enorm)
{
    const int t = threadIdx.x;
    const int rr = t >> 2, q = t & 3;
    const int row = blockIdx.x * 64 + rr;
    const float4* src = (const float4*)(emb + (size_t)row * 128 + q * 32);
    short8* dst = (short8*)(embbf + (size_t)row * 128 + q * 32);
    float nrm = 0.f;
#pragma unroll
    for (int u2 = 0; u2 < 4; ++u2) {
        float4 a = src[u2 * 2], b = src[u2 * 2 + 1];
        float f[8] = {a.x, a.y, a.z, a.w, b.x, b.y, b.z, b.w};
        union { short8 v; ushort u[8]; } p;
#pragma unroll
        for (int j = 0; j < 8; ++j) {
            nrm = fmaf(f[j], f[j], nrm);
            p.u[j] = f32_to_bf16(f[j]);
        }
        dst[u2] = p.v;
    }
    nrm += __shfl_xor(nrm, 1);
    nrm += __shfl_xor(nrm, 2);
    if (q == 0) enorm[row] = nrm;
}

// ---------------------------------------------------------------------------
// kA2: bf16-MFMA candidate pass. Block = 128 threads (2 waves x 32 rows).
// All 1024 cols per block via 8 LDS tiles of 128 cols (32KB, XOR-swizzled
// at 16B granularity so staging writes and B-frag reads are bank-uniform).
// Score s = ||e||^2 - 2*x.e packed to sortable key (dist22<<10 | col);
// per-lane top-3 via 5-op min/max ladder; merged top-8 guard band -> cand8.
// Exact fp64 refine (kB) fixes any bf16/truncation rank noise.
// ---------------------------------------------------------------------------
__global__ __launch_bounds__(128) void kA2_candidates(
    const ushort* __restrict__ xbf, const ushort* __restrict__ embbf,
    const float* __restrict__ enorm, int* __restrict__ cand8)
{
    __shared__ uint4 et16[2048];      // 32KB emb tile, aliased as merge buffer
    __shared__ float enl[1024];       // 4KB emb norms
    uint* keybuf = (uint*)et16;

    const int t    = threadIdx.x;
    const int lane = t & 63, w = t >> 6;
    const int quad = lane >> 4, m = lane & 15;
    const int rowBase = blockIdx.x * 64;
    const int rw = rowBase + w * 32;

    for (int i = t; i < 1024; i += 128) enl[i] = enorm[i];

    // A fragments for this wave's 32 rows, full K=128, kept in registers.
    // mfma_f32_16x16x32_bf16 A-frag: lane holds A[m=lane&15][k=quad*8+j].
    short8 A[2][4];
#pragma unroll
    for (int s = 0; s < 2; ++s)
#pragma unroll
    for (int kk = 0; kk < 4; ++kk)
        A[s][kk] = *(const short8*)(xbf + (size_t)(rw + s * 16 + m) * 128 + kk * 32 + quad * 8);

    uint kq[2][4][3];
#pragma unroll
    for (int s = 0; s < 2; ++s)
#pragma unroll
    for (int i = 0; i < 4; ++i)
        kq[s][i][0] = kq[s][i][1] = kq[s][i][2] = 0xFFFFFFFFu;

    const uint4* eg = (const uint4*)embbf;

    for (int tile = 0; tile < 8; ++tile) {
        __syncthreads();
        // stage 128 emb rows (32KB) with 16B-chunk XOR swizzle
#pragma unroll
        for (int u = 0; u < 16; ++u) {
            int c = u * 128 + t;
            int row = c >> 4, kb = c & 15;
            et16[row * 16 + (kb ^ (row & 7))] = eg[(size_t)(tile * 128 + row) * 16 + kb];
        }
        __syncthreads();
#pragma unroll
        for (int sub = 0; sub < 8; ++sub) {
            f32x4 acc0 = {0.f, 0.f, 0.f, 0.f}, acc1 = {0.f, 0.f, 0.f, 0.f};
#pragma unroll
            for (int kk = 0; kk < 4; ++kk) {
                // B-frag: lane holds emb[col = sub*16+m][k = kk*32+quad*8 ..+7]
                short8 B = *(const short8*)&et16[(sub * 16 + m) * 16 + ((kk * 4 + quad) ^ (m & 7))];
                acc0 = __builtin_amdgcn_mfma_f32_16x16x32_bf16(A[0][kk], B, acc0, 0, 0, 0);
                acc1 = __builtin_amdgcn_mfma_f32_16x16x32_bf16(A[1][kk], B, acc1, 0, 0, 0);
            }
            const int col = tile * 128 + sub * 16 + m;
            const float en = enl[col];
#pragma unroll
            for (int i = 0; i < 4; ++i) {
                {
                    float sc = fmaf(-2.f, acc0[i], en);
                    uint u = __float_as_uint(sc);
                    u ^= (uint)(((int)u) >> 31) | 0x80000000u;   // sortable
                    uint key = (u & 0xFFFFFC00u) | (uint)col;
                    uint t0 = max(kq[0][i][0], key); kq[0][i][0] = min(kq[0][i][0], key);
                    uint t1 = max(kq[0][i][1], t0);  kq[0][i][1] = min(kq[0][i][1], t0);
                    kq[0][i][2] = min(kq[0][i][2], t1);
                }
                {
                    float sc = fmaf(-2.f, acc1[i], en);
                    uint u = __float_as_uint(sc);
                    u ^= (uint)(((int)u) >> 31) | 0x80000000u;
                    uint key = (u & 0xFFFFFC00u) | (uint)col;
                    uint t0 = max(kq[1][i][0], key); kq[1][i][0] = min(kq[1][i][0], key);
                    uint t1 = max(kq[1][i][1], t0);  kq[1][i][1] = min(kq[1][i][1], t0);
                    kq[1][i][2] = min(kq[1][i][2], t1);
                }
            }
        }
    }

    __syncthreads();
    // dump per-lane top-3: slot-major layout, stride 65 (bank-friendly both ways)
#pragma unroll
    for (int s = 0; s < 2; ++s)
#pragma unroll
    for (int i = 0; i < 4; ++i) {
        int rowl = w * 32 + s * 16 + quad * 4 + i;   // C row = quad*4 + reg
#pragma unroll
        for (int j = 0; j < 3; ++j)
            keybuf[(m * 3 + j) * 65 + rowl] = kq[s][i][j];
    }
    __syncthreads();

    if (t < 64) {
        uint D[8];
#pragma unroll
        for (int s = 0; s < 8; ++s) D[s] = 0xFFFFFFFFu;
        for (int s = 0; s < 48; ++s) {
            uint k = keybuf[s * 65 + t];
            if (k < D[7]) {
                D[7] = k;
#pragma unroll
                for (int u = 7; u > 0; --u)
                    if (D[u] < D[u - 1]) { uint tmp = D[u]; D[u] = D[u - 1]; D[u - 1] = tmp; }
            }
        }
        int n = rowBase + t;
#pragma unroll
        for (int s = 0; s < 8; ++s) cand8[n * 8 + s] = (int)(D[s] & 1023u);
    }
}

// ---------------------------------------------------------------------------
// Kernel B: fp64 exact refine of 8 candidates -> true top-3 (tie-break by
// lower index, matching jax.lax.top_k stability). Also builds the histogram
// of the 3rd-nearest index for perplexity.
// ---------------------------------------------------------------------------
__global__ __launch_bounds__(256) void kB_refine(
    const float* __restrict__ in, const float* __restrict__ emb,
    const int* __restrict__ cand8, int* __restrict__ top3, int* __restrict__ hist)
{
    __shared__ float x_lds[8192];   // [128][64]
    const int t = threadIdx.x;
    const int rowBase = blockIdx.x * 64;
    const int b = rowBase >> 10, hw0 = rowBase & 1023;
    const float* inB = in + (size_t)b * (CC * HW) + hw0;
    for (int i = t; i < 8192; i += 256) {
        int c = i >> 6, r = i & 63;
        x_lds[c * 64 + r] = inB[c * HW + r];
    }
    __syncthreads();

    const int r = t >> 2;     // row 0..63
    const int q = t & 3;      // c-chunk of 32
    const int n = rowBase + r;

    double dist[8]; int es[8];
    for (int s = 0; s < 8; ++s) {
        int e = cand8[n * 8 + s];
        es[s] = e;
        const float4* er = (const float4*)(emb + (size_t)e * DD + q * 32);
        double acc = 0.0;
#pragma unroll
        for (int u = 0; u < 8; ++u) {
            float4 ev = er[u];
            int c0 = q * 32 + u * 4;
            double a0 = (double)x_lds[(c0 + 0) * 64 + r] - (double)ev.x;
            double a1 = (double)x_lds[(c0 + 1) * 64 + r] - (double)ev.y;
            double a2 = (double)x_lds[(c0 + 2) * 64 + r] - (double)ev.z;
            double a3 = (double)x_lds[(c0 + 3) * 64 + r] - (double)ev.w;
            acc += a0 * a0 + a1 * a1 + a2 * a2 + a3 * a3;
        }
        acc += __shfl_xor(acc, 1);
        acc += __shfl_xor(acc, 2);
        dist[s] = acc;
    }

    if (q == 0) {
        bool used[8] = {false, false, false, false, false, false, false, false};
        int out_idx[3];
#pragma unroll
        for (int p = 0; p < 3; ++p) {
            double bd = 1.0e300; int bi = 0x7fffffff, bs = 0;
            for (int s = 0; s < 8; ++s) {
                if (used[s]) continue;
                if (dist[s] < bd || (dist[s] == bd && es[s] < bi)) {
                    bd = dist[s]; bi = es[s]; bs = s;
                }
            }
            used[bs] = true; out_idx[p] = bi;
        }
        top3[n * 4 + 0] = out_idx[0];
        top3[n * 4 + 1] = out_idx[1];
        top3[n * 4 + 2] = out_idx[2];
        atomicAdd(&hist[out_idx[2]], 1);
    }
}

// ---------------------------------------------------------------------------
// Kernel C: quantized_nchw write (gather emb[idx0][c]) + fp64 loss partials.
// ---------------------------------------------------------------------------
__global__ __launch_bounds__(256) void kC_quant_loss(
    const float* __restrict__ in, const float* __restrict__ emb,
    const int* __restrict__ top3, float* __restrict__ out,
    double* __restrict__ partials)
{
    const int t = threadIdx.x, bid = blockIdx.x;
    double acc = 0.0;
#pragma unroll
    for (int u = 0; u < 4; ++u) {
        int j  = bid * 1024 + u * 256 + t;
        int hw = j & 1023;
        int c  = (j >> 10) & 127;
        int bb = j >> 17;
        int n  = bb * 1024 + hw;
        int e  = top3[n * 4];
        float qv = emb[e * DD + c];
        float xv = in[j];
        out[OFF_QUANT + j] = qv;
        double d = (double)qv - (double)xv;
        acc += d * d;
    }
#pragma unroll
    for (int o = 1; o < 64; o <<= 1) acc += __shfl_xor(acc, o);
    __shared__ double wsum[4];
    if ((t & 63) == 0) wsum[t >> 6] = acc;
    __syncthreads();
    if (t == 0) partials[bid] = wsum[0] + wsum[1] + wsum[2] + wsum[3];
}

// ---------------------------------------------------------------------------
// Kernel D: top_k_quantized [3][N][128] — coalesced float2 gather/store.
// (Also overwrites the xbf scratch that lived in this output region.)
// ---------------------------------------------------------------------------
__global__ __launch_bounds__(256) void kD_topk(
    const float* __restrict__ emb, const int* __restrict__ top3,
    float* __restrict__ out)
{
    int j  = blockIdx.x * 256 + threadIdx.x;   // float2 units, 3*32768*64 total
    int c2 = j & 63;
    int n  = (j >> 6) & 32767;
    int k  = j >> 21;
    int e  = top3[n * 4 + k];
    const float2* e2 = (const float2*)emb;
    ((float2*)(out + OFF_TOPK))[j] = e2[e * 64 + c2];
}

// ---------------------------------------------------------------------------
// Kernel E: encodings scatter (region pre-zeroed by memset).
// ---------------------------------------------------------------------------
__global__ __launch_bounds__(256) void kE_scatter(
    const int* __restrict__ top3, float* __restrict__ out)
{
    int n = blockIdx.x * 256 + threadIdx.x;
    int e = top3[n * 4 + 2];
    out[(size_t)OFF_ENC + (size_t)n * KK + e] = 1.0f;
}

// ---------------------------------------------------------------------------
// Kernel F: finalize loss + perplexity (fp64 reductions).
// ---------------------------------------------------------------------------
__global__ __launch_bounds__(1024) void kF_final(
    const double* __restrict__ partials, const int* __restrict__ hist,
    float* __restrict__ out)
{
    __shared__ double sred[1024];
    const int t = threadIdx.x;
    double a = partials[t] + partials[t + 1024] + partials[t + 2048] + partials[t + 3072];
    sred[t] = a;
    __syncthreads();
    for (int s = 512; s > 0; s >>= 1) {
        if (t < s) sred[t] += sred[t + s];
        __syncthreads();
    }
    if (t == 0) out[0] = (float)(0.25 * sred[0] / 4194304.0);
    __syncthreads();
    double p = (double)hist[t] / 32768.0;
    sred[t] = p * log(p + 1e-10);
    __syncthreads();
    for (int s = 512; s > 0; s >>= 1) {
        if (t < s) sred[t] += sred[t + s];
        __syncthreads();
    }
    if (t == 0) out[OFF_PERP] = (float)exp(-sred[0]);
}

extern "C" void kernel_launch(void* const* d_in, const int* in_sizes, int n_in,
                              void* d_out, int out_size, void* d_ws, size_t ws_size,
                              hipStream_t stream)
{
    const float* in  = (const float*)d_in[0];
    const float* emb = (const float*)d_in[1];
    float* out = (float*)d_out;
    char*  ws  = (char*)d_ws;

    double* partials = (double*)(ws + WS_PARTIALS);
    int*    hist     = (int*)(ws + WS_HIST);
    int*    cand8    = (int*)(ws + WS_CAND8);
    int*    top3     = (int*)(ws + WS_TOP3);
    ushort* embbf    = (ushort*)(ws + WS_EMBBF);
    float*  enorm    = (float*)(ws + WS_ENORM);
    // xbf scratch lives in the top_k output region (+2 floats for 16B align);
    // kD_topk fully overwrites this region afterwards.
    ushort* xbf = (ushort*)(out + OFF_TOPK + 2);

    hipMemsetAsync(out + OFF_ENC, 0, (size_t)NN * KK * sizeof(float), stream);
    hipMemsetAsync(hist, 0, KK * sizeof(int), stream);

    kXe_convert  <<<dim3(16), dim3(256), 0, stream>>>(emb, embbf, enorm);
    kX_convert   <<<dim3(128), dim3(256), 0, stream>>>(in, xbf);
    kA2_candidates<<<dim3(512), dim3(128), 0, stream>>>(xbf, embbf, enorm, cand8);
    kB_refine    <<<dim3(512), dim3(256), 0, stream>>>(in, emb, cand8, top3, hist);
    kC_quant_loss<<<dim3(4096), dim3(256), 0, stream>>>(in, emb, top3, out, partials);
    kD_topk      <<<dim3(24576), dim3(256), 0, stream>>>(emb, top3, out);
    kE_scatter   <<<dim3(128), dim3(256), 0, stream>>>(top3, out);
    kF_final     <<<dim3(1), dim3(1024), 0, stream>>>(partials, hist, out);
}